// Round 1
// baseline (115.237 us; speedup 1.0000x reference)
//
#include <hip/hip_runtime.h>
#include <math.h>

#define MARGIN 0.3f
#define BIGF 1e9f
#define NN 512
#define DD 2048
#define LDIM 128
#define PARTS 8

// ---------------------------------------------------------------------------
// K1: row squared-norms of X + zero the accumulators / ticket counter
// ---------------------------------------------------------------------------
__global__ __launch_bounds__(256) void k_norms_init(
    const float* __restrict__ X, float* __restrict__ norms,
    float* gsum, float* lsum, unsigned* counter)
{
    int i = blockIdx.x;
    int t = threadIdx.x;
    const float4* xr = (const float4*)(X + (size_t)i * DD);  // 512 float4
    float4 v1 = xr[t];
    float4 v2 = xr[t + 256];
    float acc = v1.x * v1.x + v1.y * v1.y + v1.z * v1.z + v1.w * v1.w
              + v2.x * v2.x + v2.y * v2.y + v2.z * v2.z + v2.w * v2.w;
    for (int off = 32; off > 0; off >>= 1)
        acc += __shfl_down(acc, off);
    __shared__ float part[4];
    int lane = t & 63, wid = t >> 6;
    if (lane == 0) part[wid] = acc;
    __syncthreads();
    if (t == 0) {
        norms[i] = part[0] + part[1] + part[2] + part[3];
        if (i == 0) { *gsum = 0.0f; *lsum = 0.0f; *counter = 0u; }
    }
}

// ---------------------------------------------------------------------------
// K2: Gram matrix G = X X^T, fp32, 64x64 tiles, split-K = 4 partials
//     grid = 8*8*4 = 256 blocks of 256 threads
// ---------------------------------------------------------------------------
__global__ __launch_bounds__(256) void k_gram(
    const float* __restrict__ X, float* __restrict__ Gp)
{
    __shared__ float As[16][64];
    __shared__ float Bs[16][64];
    int bid = blockIdx.x;
    int tj = bid & 7;
    int ti = (bid >> 3) & 7;
    int ks = bid >> 6;           // k-slice 0..3, each 512 wide
    int tid = threadIdx.x;

    // staging indices: 4 threads per row, each loads one float4 of K
    int lr = tid >> 2;           // 0..63 row in tile
    int lc = (tid & 3) << 2;     // 0,4,8,12 k-offset in chunk
    const float* Ap = X + (size_t)(ti * 64 + lr) * DD;
    const float* Bp = X + (size_t)(tj * 64 + lr) * DD;

    // compute indices: 4x4 register tile
    int ty = tid >> 4;           // 0..15 -> rows 4*ty..4*ty+3
    int tx = tid & 15;           // 0..15 -> cols 4*tx..4*tx+3

    float acc[4][4];
#pragma unroll
    for (int r = 0; r < 4; r++)
#pragma unroll
        for (int c = 0; c < 4; c++) acc[r][c] = 0.0f;

    int k0 = ks * 512;
    for (int kc = 0; kc < 32; kc++) {
        float4 av = *(const float4*)(Ap + k0 + lc);
        float4 bv = *(const float4*)(Bp + k0 + lc);
        __syncthreads();
        As[lc + 0][lr] = av.x; As[lc + 1][lr] = av.y;
        As[lc + 2][lr] = av.z; As[lc + 3][lr] = av.w;
        Bs[lc + 0][lr] = bv.x; Bs[lc + 1][lr] = bv.y;
        Bs[lc + 2][lr] = bv.z; Bs[lc + 3][lr] = bv.w;
        __syncthreads();
#pragma unroll
        for (int kk = 0; kk < 16; kk++) {
            float4 a4 = *(const float4*)&As[kk][ty << 2];
            float4 b4 = *(const float4*)&Bs[kk][tx << 2];
            float ar[4] = {a4.x, a4.y, a4.z, a4.w};
            float br[4] = {b4.x, b4.y, b4.z, b4.w};
#pragma unroll
            for (int r = 0; r < 4; r++)
#pragma unroll
                for (int c = 0; c < 4; c++)
                    acc[r][c] = fmaf(ar[r], br[c], acc[r][c]);
        }
        k0 += 16;
    }

    float* outp = Gp + (size_t)ks * NN * NN
                + (size_t)(ti * 64 + (ty << 2)) * NN + tj * 64 + (tx << 2);
#pragma unroll
    for (int r = 0; r < 4; r++) {
        float4 v = make_float4(acc[r][0], acc[r][1], acc[r][2], acc[r][3]);
        *(float4*)(outp + (size_t)r * NN) = v;
    }
}

// ---------------------------------------------------------------------------
// K3: hard mining per row + global margin-ranking sum
// ---------------------------------------------------------------------------
__global__ __launch_bounds__(256) void k_mining(
    const float* __restrict__ Gp, const float* __restrict__ norms,
    const int* __restrict__ tg, int* __restrict__ p_inds,
    int* __restrict__ n_inds, float* gsum)
{
    int i = blockIdx.x;
    int t = threadIdx.x;
    float ni = norms[i];
    int tgt_i = tg[i];

    float apv = -BIGF; int api = 0x7fffffff;
    float anv =  BIGF; int ani = 0x7fffffff;

#pragma unroll
    for (int jj = 0; jj < 2; jj++) {
        int j = t + jj * 256;
        size_t base = (size_t)i * NN + j;
        float g = Gp[base] + Gp[base + (size_t)NN * NN]
                + Gp[base + 2ul * NN * NN] + Gp[base + 3ul * NN * NN];
        float dd = ni + norms[j] - 2.0f * g;
        float dist = sqrtf(fmaxf(dd, 1e-12f));
        bool pos = (tg[j] == tgt_i);
        float a = pos ? dist : -BIGF;
        if (a > apv || (a == apv && j < api)) { apv = a; api = j; }
        float b = pos ? BIGF : dist;
        if (b < anv || (b == anv && j < ani)) { anv = b; ani = j; }
    }
    // wave reduction, first-index tie-break (matches jnp.argmax/argmin)
    for (int off = 32; off > 0; off >>= 1) {
        float av = __shfl_down(apv, off); int ai = __shfl_down(api, off);
        if (av > apv || (av == apv && ai < api)) { apv = av; api = ai; }
        float nv = __shfl_down(anv, off); int nid = __shfl_down(ani, off);
        if (nv < anv || (nv == anv && nid < ani)) { anv = nv; ani = nid; }
    }
    __shared__ float s_apv[4]; __shared__ int s_api[4];
    __shared__ float s_anv[4]; __shared__ int s_ani[4];
    int lane = t & 63, wid = t >> 6;
    if (lane == 0) { s_apv[wid] = apv; s_api[wid] = api;
                     s_anv[wid] = anv; s_ani[wid] = ani; }
    __syncthreads();
    if (t == 0) {
        apv = s_apv[0]; api = s_api[0]; anv = s_anv[0]; ani = s_ani[0];
        for (int wv = 1; wv < 4; wv++) {
            float av = s_apv[wv]; int ai = s_api[wv];
            if (av > apv || (av == apv && ai < api)) { apv = av; api = ai; }
            float nv = s_anv[wv]; int nid = s_ani[wv];
            if (nv < anv || (nv == anv && nid < ani)) { anv = nv; ani = nid; }
        }
        p_inds[i] = api;
        n_inds[i] = ani;
        atomicAdd(gsum, fmaxf(0.0f, MARGIN + apv - anv));
    }
}

// ---------------------------------------------------------------------------
// K4: local distances (8x8 euclid -> tanh -> DTW) for (i,p_ind) and (i,n_ind),
//     local margin-ranking sum, last block writes both outputs.
//     block = 128 threads = 2 waves (wave0: positive, wave1: negative)
// ---------------------------------------------------------------------------
__global__ __launch_bounds__(128) void k_local(
    const float* __restrict__ LF, const int* __restrict__ p_inds,
    const int* __restrict__ n_inds, const float* gsum, float* lsum,
    unsigned* counter, float* __restrict__ out)
{
    int i = blockIdx.x;
    int tid = threadIdx.x;
    int w = tid >> 6;        // wave id: 0 = positive pair, 1 = negative pair
    int lane = tid & 63;

    __shared__ float A[LDIM * PARTS];      // lf[i], layout [d][p]
    __shared__ float B[2][LDIM * PARTS];   // lf[ind_w]
    __shared__ float dtm[2][64];
    __shared__ float res[2];

    const float4* A4 = (const float4*)(LF + (size_t)i * LDIM * PARTS);
    ((float4*)A)[tid]        = A4[tid];
    ((float4*)A)[tid + 128]  = A4[tid + 128];

    int ind = (w == 0) ? p_inds[i] : n_inds[i];
    const float4* B4 = (const float4*)(LF + (size_t)ind * LDIM * PARTS);
    float4* Bw = (float4*)B[w];
    Bw[lane]        = B4[lane];
    Bw[lane + 64]   = B4[lane + 64];
    Bw[lane + 128]  = B4[lane + 128];
    Bw[lane + 192]  = B4[lane + 192];
    __syncthreads();

    int p = lane >> 3, q = lane & 7;
    float acc = 0.0f;
    const float* Bl = B[w];
    for (int d = 0; d < LDIM; d++) {
        float diff = A[d * PARTS + p] - Bl[d * PARTS + q];
        acc = fmaf(diff, diff, acc);
    }
    float dist = sqrtf(fmaxf(acc, 1e-12f));
    dtm[w][p * 8 + q] = tanhf(0.5f * dist);
    __syncthreads();

    if (lane == 0) {
        const float* dm = dtm[w];
        float dp[8];
        dp[0] = dm[0];
        for (int j = 1; j < 8; j++) dp[j] = dp[j - 1] + dm[j];
        for (int r = 1; r < 8; r++) {
            dp[0] += dm[r * 8];
            for (int j = 1; j < 8; j++)
                dp[j] = dm[r * 8 + j] + fminf(dp[j], dp[j - 1]);
        }
        res[w] = dp[7];
    }
    __syncthreads();

    if (tid == 0) {
        float l = fmaxf(0.0f, MARGIN + res[0] - res[1]);
        atomicAdd(lsum, l);
        __threadfence();
        unsigned old = atomicAdd(counter, 1u);
        if (old == (NN - 1)) {
            float ls = atomicAdd(lsum, 0.0f);   // atomic read-back
            out[0] = (*(volatile const float*)gsum) * (1.0f / NN);
            out[1] = ls * (1.0f / NN);
        }
    }
}

// ---------------------------------------------------------------------------
extern "C" void kernel_launch(void* const* d_in, const int* in_sizes, int n_in,
                              void* d_out, int out_size, void* d_ws, size_t ws_size,
                              hipStream_t stream)
{
    const float* X  = (const float*)d_in[0];   // [512, 2048] fp32
    const int*   tg = (const int*)d_in[1];     // [512] int
    const float* LF = (const float*)d_in[2];   // [512, 128, 8] fp32
    float* out = (float*)d_out;                // 2 fp32 scalars

    char* ws = (char*)d_ws;
    float*    Gp      = (float*)ws;                         // 4*512*512 fp32 = 4 MB
    float*    norms   = (float*)(ws + 4194304);             // 512 fp32
    int*      p_inds  = (int*)  (ws + 4196352);             // 512 int
    int*      n_inds  = (int*)  (ws + 4198400);             // 512 int
    float*    gsum    = (float*)(ws + 4200448);
    float*    lsum    = (float*)(ws + 4200452);
    unsigned* counter = (unsigned*)(ws + 4200456);

    k_norms_init<<<NN, 256, 0, stream>>>(X, norms, gsum, lsum, counter);
    k_gram<<<256, 256, 0, stream>>>(X, Gp);
    k_mining<<<NN, 256, 0, stream>>>(Gp, norms, tg, p_inds, n_inds, gsum);
    k_local<<<NN, 128, 0, stream>>>(LF, p_inds, n_inds, gsum, lsum, counter, out);
}

// Round 2
// 100.296 us; speedup vs baseline: 1.1490x; 1.1490x over previous
//
#include <hip/hip_runtime.h>
#include <math.h>

#define MARGIN 0.3f
#define BIGF 1e9f
#define NN 512
#define DD 2048
#define LDIM 128
#define PARTS 8

typedef __attribute__((ext_vector_type(8))) __bf16 bf16x8;
typedef __attribute__((ext_vector_type(4))) __bf16 bf16x4;
typedef __attribute__((ext_vector_type(4))) float f32x4;

__device__ __forceinline__ void load_lds16(const void* g, void* lds) {
    __builtin_amdgcn_global_load_lds(
        (const __attribute__((address_space(1))) unsigned int*)g,
        (__attribute__((address_space(3))) unsigned int*)lds, 16, 0, 0);
}

// ---------------------------------------------------------------------------
// K1: norms + bf16 hi/lo split of X + zero accumulators
// ---------------------------------------------------------------------------
__global__ __launch_bounds__(256) void k_prep(
    const float* __restrict__ X, __bf16* __restrict__ Hhi, __bf16* __restrict__ Hlo,
    float* __restrict__ norms, float* gsum, float* lsum, unsigned* counter)
{
    int i = blockIdx.x;
    int t = threadIdx.x;
    const float4* xr = (const float4*)(X + (size_t)i * DD);
    float4 v1 = xr[t];
    float4 v2 = xr[t + 256];
    float acc = v1.x * v1.x + v1.y * v1.y + v1.z * v1.z + v1.w * v1.w
              + v2.x * v2.x + v2.y * v2.y + v2.z * v2.z + v2.w * v2.w;

    float e1[4] = {v1.x, v1.y, v1.z, v1.w};
    float e2[4] = {v2.x, v2.y, v2.z, v2.w};
    bf16x4 h1, h2, l1, l2;
#pragma unroll
    for (int j = 0; j < 4; j++) {
        __bf16 h = (__bf16)e1[j];
        h1[j] = h;
        l1[j] = (__bf16)(e1[j] - (float)h);
        __bf16 g = (__bf16)e2[j];
        h2[j] = g;
        l2[j] = (__bf16)(e2[j] - (float)g);
    }
    bf16x4* hr = (bf16x4*)(Hhi + (size_t)i * DD);
    bf16x4* lr = (bf16x4*)(Hlo + (size_t)i * DD);
    hr[t] = h1; hr[t + 256] = h2;
    lr[t] = l1; lr[t + 256] = l2;

    for (int off = 32; off > 0; off >>= 1)
        acc += __shfl_down(acc, off);
    __shared__ float part[4];
    int lane = t & 63, wid = t >> 6;
    if (lane == 0) part[wid] = acc;
    __syncthreads();
    if (t == 0) {
        norms[i] = part[0] + part[1] + part[2] + part[3];
        if (i == 0) { *gsum = 0.0f; *lsum = 0.0f; *counter = 0u; }
    }
}

// ---------------------------------------------------------------------------
// K2: G = H*H^T + H*L^T + L*H^T via bf16 MFMA, 64x64 tiles, split-K=4.
//     grid = 8*8*4 = 256 blocks x 256 threads (4 waves, each a 32x32 quadrant).
//     LDS tiles staged via global_load_lds in fragment-linear order:
//     subtile s (16 rows), slot l: row = l&15, k-chunk = (l>>4)*8.
// ---------------------------------------------------------------------------
__global__ __launch_bounds__(256) void k_gram_mfma(
    const __bf16* __restrict__ Hhi, const __bf16* __restrict__ Hlo,
    float* __restrict__ Gp)
{
    __shared__ __bf16 Ah[2048], Al[2048], Bh[2048], Bl[2048];  // 4x 64x32 tiles

    int bid = blockIdx.x;
    int tj = bid & 7;
    int ti = (bid >> 3) & 7;
    int ks = bid >> 6;
    int t = threadIdx.x;
    int w = t >> 6, lane = t & 63;
    int wr = w >> 1, wc = w & 1;

    // staging: wave w stages subtile w of each of the 4 tiles
    int row16 = (w << 4) + (lane & 15);
    int kchunk = (lane >> 4) << 3;
    size_t kc0 = (size_t)(ks * 512 + kchunk);
    const __bf16* pAh = Hhi + (size_t)(ti * 64 + row16) * DD + kc0;
    const __bf16* pAl = Hlo + (size_t)(ti * 64 + row16) * DD + kc0;
    const __bf16* pBh = Hhi + (size_t)(tj * 64 + row16) * DD + kc0;
    const __bf16* pBl = Hlo + (size_t)(tj * 64 + row16) * DD + kc0;
    __bf16* ldsAh = &Ah[w * 512];
    __bf16* ldsAl = &Al[w * 512];
    __bf16* ldsBh = &Bh[w * 512];
    __bf16* ldsBl = &Bl[w * 512];

    f32x4 acc00 = {0.f, 0.f, 0.f, 0.f};
    f32x4 acc01 = {0.f, 0.f, 0.f, 0.f};
    f32x4 acc10 = {0.f, 0.f, 0.f, 0.f};
    f32x4 acc11 = {0.f, 0.f, 0.f, 0.f};

    for (int it = 0; it < 16; ++it) {
        load_lds16(pAh, ldsAh);
        load_lds16(pBh, ldsBh);
        load_lds16(pAl, ldsAl);
        load_lds16(pBl, ldsBl);
        pAh += 32; pAl += 32; pBh += 32; pBl += 32;
        __syncthreads();   // drains vmcnt(0): staged data visible

        const bf16x8* fAh = (const bf16x8*)&Ah[wr * 1024];
        const bf16x8* fAl = (const bf16x8*)&Al[wr * 1024];
        const bf16x8* fBh = (const bf16x8*)&Bh[wc * 1024];
        const bf16x8* fBl = (const bf16x8*)&Bl[wc * 1024];
        bf16x8 ah0 = fAh[lane], ah1 = fAh[lane + 64];
        bf16x8 al0 = fAl[lane], al1 = fAl[lane + 64];
        bf16x8 bh0 = fBh[lane], bh1 = fBh[lane + 64];
        bf16x8 bl0 = fBl[lane], bl1 = fBl[lane + 64];

        acc00 = __builtin_amdgcn_mfma_f32_16x16x32_bf16(ah0, bh0, acc00, 0, 0, 0);
        acc00 = __builtin_amdgcn_mfma_f32_16x16x32_bf16(ah0, bl0, acc00, 0, 0, 0);
        acc00 = __builtin_amdgcn_mfma_f32_16x16x32_bf16(al0, bh0, acc00, 0, 0, 0);

        acc01 = __builtin_amdgcn_mfma_f32_16x16x32_bf16(ah0, bh1, acc01, 0, 0, 0);
        acc01 = __builtin_amdgcn_mfma_f32_16x16x32_bf16(ah0, bl1, acc01, 0, 0, 0);
        acc01 = __builtin_amdgcn_mfma_f32_16x16x32_bf16(al0, bh1, acc01, 0, 0, 0);

        acc10 = __builtin_amdgcn_mfma_f32_16x16x32_bf16(ah1, bh0, acc10, 0, 0, 0);
        acc10 = __builtin_amdgcn_mfma_f32_16x16x32_bf16(ah1, bl0, acc10, 0, 0, 0);
        acc10 = __builtin_amdgcn_mfma_f32_16x16x32_bf16(al1, bh0, acc10, 0, 0, 0);

        acc11 = __builtin_amdgcn_mfma_f32_16x16x32_bf16(ah1, bh1, acc11, 0, 0, 0);
        acc11 = __builtin_amdgcn_mfma_f32_16x16x32_bf16(ah1, bl1, acc11, 0, 0, 0);
        acc11 = __builtin_amdgcn_mfma_f32_16x16x32_bf16(al1, bh1, acc11, 0, 0, 0);
        __syncthreads();   // all waves done reading before next stage
    }

    // epilogue: C/D layout col=lane&15, row=(lane>>4)*4+reg
    int rbase = ti * 64 + wr * 32 + ((lane >> 4) << 2);
    int cbase = tj * 64 + wc * 32 + (lane & 15);
    float* gb = Gp + (size_t)ks * NN * NN;
    f32x4 accs[2][2] = {{acc00, acc01}, {acc10, acc11}};
#pragma unroll
    for (int g = 0; g < 2; g++)
#pragma unroll
        for (int h = 0; h < 2; h++)
#pragma unroll
            for (int r = 0; r < 4; r++)
                gb[(size_t)(rbase + g * 16 + r) * NN + cbase + h * 16] = accs[g][h][r];
}

// ---------------------------------------------------------------------------
// K3: fused hard mining + local DTW loss + finalize (ticket)
// ---------------------------------------------------------------------------
__global__ __launch_bounds__(256) void k_mine_local(
    const float* __restrict__ Gp, const float* __restrict__ norms,
    const int* __restrict__ tg, const float* __restrict__ LF,
    float* gsum, float* lsum, unsigned* counter, float* __restrict__ out)
{
    __shared__ float s_apv[4]; __shared__ int s_api[4];
    __shared__ float s_anv[4]; __shared__ int s_ani[4];
    __shared__ int sh_pn[2];
    __shared__ float A[LDIM * PARTS];
    __shared__ float B[2][LDIM * PARTS];
    __shared__ float dtm[2][64];
    __shared__ float res[2];

    int i = blockIdx.x;
    int t = threadIdx.x;
    float ni = norms[i];
    int tgt_i = tg[i];

    float apv = -BIGF; int api = 0x7fffffff;
    float anv =  BIGF; int ani = 0x7fffffff;

#pragma unroll
    for (int jj = 0; jj < 2; jj++) {
        int j = t + jj * 256;
        size_t base = (size_t)i * NN + j;
        float g = Gp[base] + Gp[base + (size_t)NN * NN]
                + Gp[base + 2ul * NN * NN] + Gp[base + 3ul * NN * NN];
        float dd = ni + norms[j] - 2.0f * g;
        float dist = sqrtf(fmaxf(dd, 1e-12f));
        bool pos = (tg[j] == tgt_i);
        float a = pos ? dist : -BIGF;
        if (a > apv || (a == apv && j < api)) { apv = a; api = j; }
        float b = pos ? BIGF : dist;
        if (b < anv || (b == anv && j < ani)) { anv = b; ani = j; }
    }
    for (int off = 32; off > 0; off >>= 1) {
        float av = __shfl_down(apv, off); int ai = __shfl_down(api, off);
        if (av > apv || (av == apv && ai < api)) { apv = av; api = ai; }
        float nv = __shfl_down(anv, off); int nid = __shfl_down(ani, off);
        if (nv < anv || (nv == anv && nid < ani)) { anv = nv; ani = nid; }
    }
    int lane = t & 63, wid = t >> 6;
    if (lane == 0) { s_apv[wid] = apv; s_api[wid] = api;
                     s_anv[wid] = anv; s_ani[wid] = ani; }
    __syncthreads();
    if (t == 0) {
        apv = s_apv[0]; api = s_api[0]; anv = s_anv[0]; ani = s_ani[0];
        for (int wv = 1; wv < 4; wv++) {
            float av = s_apv[wv]; int ai = s_api[wv];
            if (av > apv || (av == apv && ai < api)) { apv = av; api = ai; }
            float nv = s_anv[wv]; int nid = s_ani[wv];
            if (nv < anv || (nv == anv && nid < ani)) { anv = nv; ani = nid; }
        }
        sh_pn[0] = api;
        sh_pn[1] = ani;
        atomicAdd(gsum, fmaxf(0.0f, MARGIN + apv - anv));
    }
    __syncthreads();

    // phase 2: local DTW loss. wave 0 = positive pair, wave 1 = negative pair.
    int w = t >> 6;
    ((float4*)A)[t] = ((const float4*)(LF + (size_t)i * LDIM * PARTS))[t];
    if (w < 2) {
        int ind = sh_pn[w];
        const float4* B4 = (const float4*)(LF + (size_t)ind * LDIM * PARTS);
        float4* Bw = (float4*)B[w];
        Bw[lane]       = B4[lane];
        Bw[lane + 64]  = B4[lane + 64];
        Bw[lane + 128] = B4[lane + 128];
        Bw[lane + 192] = B4[lane + 192];
    }
    __syncthreads();

    if (w < 2) {
        int p = lane >> 3, q = lane & 7;
        float acc = 0.0f;
        const float* Bw = B[w];
        for (int d = 0; d < LDIM; d++) {
            float diff = A[d * PARTS + p] - Bw[d * PARTS + q];
            acc = fmaf(diff, diff, acc);
        }
        float dist = sqrtf(fmaxf(acc, 1e-12f));
        dtm[w][p * 8 + q] = tanhf(0.5f * dist);
    }
    __syncthreads();

    if ((t == 0) || (t == 64)) {
        const float* dm = dtm[w];
        float dp[8];
        dp[0] = dm[0];
        for (int j = 1; j < 8; j++) dp[j] = dp[j - 1] + dm[j];
        for (int r = 1; r < 8; r++) {
            dp[0] += dm[r * 8];
            for (int j = 1; j < 8; j++)
                dp[j] = dm[r * 8 + j] + fminf(dp[j], dp[j - 1]);
        }
        res[w] = dp[7];
    }
    __syncthreads();

    if (t == 0) {
        float l = fmaxf(0.0f, MARGIN + res[0] - res[1]);
        atomicAdd(lsum, l);
        __threadfence();
        unsigned old = atomicAdd(counter, 1u);
        if (old == (NN - 1)) {
            __threadfence();
            float ls = atomicAdd(lsum, 0.0f);
            float gs = atomicAdd(gsum, 0.0f);
            out[0] = gs * (1.0f / NN);
            out[1] = ls * (1.0f / NN);
        }
    }
}

// ---------------------------------------------------------------------------
extern "C" void kernel_launch(void* const* d_in, const int* in_sizes, int n_in,
                              void* d_out, int out_size, void* d_ws, size_t ws_size,
                              hipStream_t stream)
{
    const float* X  = (const float*)d_in[0];   // [512, 2048] fp32
    const int*   tg = (const int*)d_in[1];     // [512] int
    const float* LF = (const float*)d_in[2];   // [512, 128, 8] fp32
    float* out = (float*)d_out;                // 2 fp32 scalars

    char* ws = (char*)d_ws;
    float*    Gp      = (float*)ws;                          // 4 * 512*512 fp32 = 4 MB
    __bf16*   Hhi     = (__bf16*)(ws + (4u << 20));          // 2 MB
    __bf16*   Hlo     = (__bf16*)(ws + (6u << 20));          // 2 MB
    float*    norms   = (float*)(ws + (8u << 20));           // 2 KB
    float*    gsum    = (float*)(ws + (8u << 20) + 4096);
    float*    lsum    = (float*)(ws + (8u << 20) + 4100);
    unsigned* counter = (unsigned*)(ws + (8u << 20) + 4104);

    k_prep<<<NN, 256, 0, stream>>>(X, Hhi, Hlo, norms, gsum, lsum, counter);
    k_gram_mfma<<<256, 256, 0, stream>>>(Hhi, Hlo, Gp);
    k_mine_local<<<NN, 256, 0, stream>>>(Gp, norms, tg, LF, gsum, lsum, counter, out);
}

// Round 3
// 96.928 us; speedup vs baseline: 1.1889x; 1.0348x over previous
//
#include <hip/hip_runtime.h>
#include <math.h>

#define MARGIN 0.3f
#define BIGF 1e9f
#define NN 512
#define DD 2048
#define LDIM 128
#define PARTS 8

typedef __attribute__((ext_vector_type(8))) __bf16 bf16x8;
typedef __attribute__((ext_vector_type(4))) float f32x4;

__device__ __forceinline__ void cvt8(const float4 a, const float4 b,
                                     bf16x8& h, bf16x8& l) {
    float f[8] = {a.x, a.y, a.z, a.w, b.x, b.y, b.z, b.w};
#pragma unroll
    for (int e = 0; e < 8; e++) {
        __bf16 hh = (__bf16)f[e];
        h[e] = hh;
        l[e] = (__bf16)(f[e] - (float)hh);
    }
}

// ---------------------------------------------------------------------------
// K1: G = X X^T via bf16 hi/lo MFMA, fp32 staged + converted in-kernel.
//     grid = 8(tj) x 8(ti) x 8(ks) = 512 blocks, 256 thr, 2 blocks/CU.
//     Per block: 64x64 tile, K-slice 256, 4 iters of K=64 (2 MFMA ksteps).
//     Fragment-linear LDS: elem(r,kk) at kstep*2048 + (r>>4)*512
//                          + ((r&15) + ((kk&31)>>3)*16)*8 + (kk&7).
//     Diagonal tiles also emit ndiag[ks][row] = partial ||x_row||^2.
// ---------------------------------------------------------------------------
__global__ __launch_bounds__(256, 2) void k_gram(
    const float* __restrict__ X, float* __restrict__ Gp,
    float* __restrict__ ndiag, float* gsum, float* lsum, unsigned* counter)
{
    __shared__ __bf16 Ah[4096], Al[4096], Bh[4096], Bl[4096];  // 32 KB

    int bid = blockIdx.x;
    int tj = bid & 7, ti = (bid >> 3) & 7, ks = bid >> 6;
    int t = threadIdx.x;
    int w = t >> 6, lane = t & 63;
    int wr = w >> 1, wc = w & 1;

    if (bid == 0 && t == 0) { *gsum = 0.0f; *lsum = 0.0f; *counter = 0u; }

    // staging role: m = matrix (0:A rows ti*64.., 1:B rows tj*64..),
    // r = row in tile, kst = which 32-wide half of the 64-wide K chunk
    int m = t >> 7;
    int r = (t >> 1) & 63;
    int kst = t & 1;
    int grow = (m ? tj : ti) * 64 + r;
    const float4* gp4 = (const float4*)(X + (size_t)grow * DD + ks * 256 + kst * 32);
    int ebase = kst * 2048 + (r >> 4) * 512 + (r & 15) * 8;
    __bf16* hb = (m ? Bh : Ah) + ebase;
    __bf16* lb = (m ? Bl : Al) + ebase;

    float4 cur[8];
#pragma unroll
    for (int q = 0; q < 8; q++) cur[q] = gp4[q];

    f32x4 acc00 = {0.f, 0.f, 0.f, 0.f};
    f32x4 acc01 = {0.f, 0.f, 0.f, 0.f};
    f32x4 acc10 = {0.f, 0.f, 0.f, 0.f};
    f32x4 acc11 = {0.f, 0.f, 0.f, 0.f};

#pragma unroll
    for (int it = 0; it < 4; ++it) {
        if (it > 0) __syncthreads();          // previous iter's readers done
#pragma unroll
        for (int jg = 0; jg < 4; jg++) {      // 4 k-groups of 8 within the 32
            bf16x8 h, l;
            cvt8(cur[2 * jg], cur[2 * jg + 1], h, l);
            *(bf16x8*)(hb + jg * 128) = h;
            *(bf16x8*)(lb + jg * 128) = l;
        }
        if (it < 3) {                          // prefetch next 64-wide K chunk
            const float4* np = gp4 + (it + 1) * 16;
#pragma unroll
            for (int q = 0; q < 8; q++) cur[q] = np[q];
        }
        __syncthreads();                       // staged data visible

#pragma unroll
        for (int kstep = 0; kstep < 2; kstep++) {
            const bf16x8* fAh = (const bf16x8*)&Ah[kstep * 2048 + wr * 1024];
            const bf16x8* fAl = (const bf16x8*)&Al[kstep * 2048 + wr * 1024];
            const bf16x8* fBh = (const bf16x8*)&Bh[kstep * 2048 + wc * 1024];
            const bf16x8* fBl = (const bf16x8*)&Bl[kstep * 2048 + wc * 1024];
            bf16x8 ah0 = fAh[lane], ah1 = fAh[lane + 64];
            bf16x8 al0 = fAl[lane], al1 = fAl[lane + 64];
            bf16x8 bh0 = fBh[lane], bh1 = fBh[lane + 64];
            bf16x8 bl0 = fBl[lane], bl1 = fBl[lane + 64];

            acc00 = __builtin_amdgcn_mfma_f32_16x16x32_bf16(ah0, bh0, acc00, 0, 0, 0);
            acc00 = __builtin_amdgcn_mfma_f32_16x16x32_bf16(ah0, bl0, acc00, 0, 0, 0);
            acc00 = __builtin_amdgcn_mfma_f32_16x16x32_bf16(al0, bh0, acc00, 0, 0, 0);

            acc01 = __builtin_amdgcn_mfma_f32_16x16x32_bf16(ah0, bh1, acc01, 0, 0, 0);
            acc01 = __builtin_amdgcn_mfma_f32_16x16x32_bf16(ah0, bl1, acc01, 0, 0, 0);
            acc01 = __builtin_amdgcn_mfma_f32_16x16x32_bf16(al0, bh1, acc01, 0, 0, 0);

            acc10 = __builtin_amdgcn_mfma_f32_16x16x32_bf16(ah1, bh0, acc10, 0, 0, 0);
            acc10 = __builtin_amdgcn_mfma_f32_16x16x32_bf16(ah1, bl0, acc10, 0, 0, 0);
            acc10 = __builtin_amdgcn_mfma_f32_16x16x32_bf16(al1, bh0, acc10, 0, 0, 0);

            acc11 = __builtin_amdgcn_mfma_f32_16x16x32_bf16(ah1, bh1, acc11, 0, 0, 0);
            acc11 = __builtin_amdgcn_mfma_f32_16x16x32_bf16(ah1, bl1, acc11, 0, 0, 0);
            acc11 = __builtin_amdgcn_mfma_f32_16x16x32_bf16(al1, bh1, acc11, 0, 0, 0);
        }
    }

    // epilogue: C/D layout col = lane&15, row = (lane>>4)*4 + reg
    int rbase = ti * 64 + wr * 32 + ((lane >> 4) << 2);
    int cbase = tj * 64 + wc * 32 + (lane & 15);
    float* gb = Gp + (size_t)ks * NN * NN;
    f32x4 accs[2][2] = {{acc00, acc01}, {acc10, acc11}};
#pragma unroll
    for (int g = 0; g < 2; g++)
#pragma unroll
        for (int h = 0; h < 2; h++)
#pragma unroll
            for (int rr = 0; rr < 4; rr++)
                gb[(size_t)(rbase + g * 16 + rr) * NN + cbase + h * 16] = accs[g][h][rr];

    // diagonal harvest: lanes holding row==col in diagonal tiles
    if (ti == tj && wr == wc && ((lane >> 4) == ((lane & 15) >> 2))) {
        int rr = lane & 3;
        int row0 = rbase + rr;                 // == cbase for these lanes
        ndiag[ks * NN + row0]      = acc00[rr];
        ndiag[ks * NN + row0 + 16] = acc11[rr];
    }
}

// ---------------------------------------------------------------------------
// K2: fused hard mining (norms from ndiag) + local DTW loss + finalize
// ---------------------------------------------------------------------------
__global__ __launch_bounds__(256) void k_mine_local(
    const float* __restrict__ Gp, const float* __restrict__ ndiag,
    const int* __restrict__ tg, const float* __restrict__ LF,
    float* gsum, float* lsum, unsigned* counter, float* __restrict__ out)
{
    __shared__ float sdiag[NN];
    __shared__ float s_apv[4]; __shared__ int s_api[4];
    __shared__ float s_anv[4]; __shared__ int s_ani[4];
    __shared__ int sh_pn[2];
    __shared__ float A[LDIM * PARTS];
    __shared__ float B[2][LDIM * PARTS];
    __shared__ float dtm[2][64];
    __shared__ float res[2];

    int i = blockIdx.x;
    int t = threadIdx.x;

    float d0 = 0.f, d1 = 0.f;
#pragma unroll
    for (int ks = 0; ks < 8; ks++) {
        d0 += ndiag[ks * NN + t];
        d1 += ndiag[ks * NN + t + 256];
    }
    sdiag[t] = d0;
    sdiag[t + 256] = d1;
    __syncthreads();

    float ni = sdiag[i];
    int tgt_i = tg[i];

    float apv = -BIGF; int api = 0x7fffffff;
    float anv =  BIGF; int ani = 0x7fffffff;

#pragma unroll
    for (int jj = 0; jj < 2; jj++) {
        int j = t + jj * 256;
        float g = 0.f;
#pragma unroll
        for (int ks = 0; ks < 8; ks++)
            g += Gp[(size_t)ks * NN * NN + (size_t)i * NN + j];
        float nj = (jj == 0) ? d0 : d1;
        float dd = ni + nj - 2.0f * g;
        float dist = sqrtf(fmaxf(dd, 1e-12f));
        bool pos = (tg[j] == tgt_i);
        float a = pos ? dist : -BIGF;
        if (a > apv || (a == apv && j < api)) { apv = a; api = j; }
        float b = pos ? BIGF : dist;
        if (b < anv || (b == anv && j < ani)) { anv = b; ani = j; }
    }
    // wave reduction with first-index tie-break (matches jnp.argmax/argmin)
    for (int off = 32; off > 0; off >>= 1) {
        float av = __shfl_down(apv, off); int ai = __shfl_down(api, off);
        if (av > apv || (av == apv && ai < api)) { apv = av; api = ai; }
        float nv = __shfl_down(anv, off); int nid = __shfl_down(ani, off);
        if (nv < anv || (nv == anv && nid < ani)) { anv = nv; ani = nid; }
    }
    int lane = t & 63, wid = t >> 6;
    if (lane == 0) { s_apv[wid] = apv; s_api[wid] = api;
                     s_anv[wid] = anv; s_ani[wid] = ani; }
    __syncthreads();
    if (t == 0) {
        apv = s_apv[0]; api = s_api[0]; anv = s_anv[0]; ani = s_ani[0];
        for (int wv = 1; wv < 4; wv++) {
            float av = s_apv[wv]; int ai = s_api[wv];
            if (av > apv || (av == apv && ai < api)) { apv = av; api = ai; }
            float nv = s_anv[wv]; int nid = s_ani[wv];
            if (nv < anv || (nv == anv && nid < ani)) { anv = nv; ani = nid; }
        }
        sh_pn[0] = api;
        sh_pn[1] = ani;
        atomicAdd(gsum, fmaxf(0.0f, MARGIN + apv - anv));
    }
    __syncthreads();

    // phase 2: local DTW loss. wave 0 = positive pair, wave 1 = negative pair.
    int w = t >> 6;
    ((float4*)A)[t] = ((const float4*)(LF + (size_t)i * LDIM * PARTS))[t];
    if (w < 2) {
        int ind = sh_pn[w];
        const float4* B4 = (const float4*)(LF + (size_t)ind * LDIM * PARTS);
        float4* Bw = (float4*)B[w];
        Bw[lane]       = B4[lane];
        Bw[lane + 64]  = B4[lane + 64];
        Bw[lane + 128] = B4[lane + 128];
        Bw[lane + 192] = B4[lane + 192];
    }
    __syncthreads();

    if (w < 2) {
        int p = lane >> 3, q = lane & 7;
        float acc = 0.0f;
        const float* Bw = B[w];
        for (int d = 0; d < LDIM; d++) {
            float diff = A[d * PARTS + p] - Bw[d * PARTS + q];
            acc = fmaf(diff, diff, acc);
        }
        float dist = sqrtf(fmaxf(acc, 1e-12f));
        dtm[w][p * 8 + q] = tanhf(0.5f * dist);
    }
    __syncthreads();

    if ((t == 0) || (t == 64)) {
        const float* dm = dtm[w];
        float dp[8];
        dp[0] = dm[0];
        for (int j = 1; j < 8; j++) dp[j] = dp[j - 1] + dm[j];
        for (int rr = 1; rr < 8; rr++) {
            dp[0] += dm[rr * 8];
            for (int j = 1; j < 8; j++)
                dp[j] = dm[rr * 8 + j] + fminf(dp[j], dp[j - 1]);
        }
        res[w] = dp[7];
    }
    __syncthreads();

    if (t == 0) {
        float l = fmaxf(0.0f, MARGIN + res[0] - res[1]);
        atomicAdd(lsum, l);
        __threadfence();
        unsigned old = atomicAdd(counter, 1u);
        if (old == (NN - 1)) {
            __threadfence();
            float ls = atomicAdd(lsum, 0.0f);
            float gs = atomicAdd(gsum, 0.0f);
            out[0] = gs * (1.0f / NN);
            out[1] = ls * (1.0f / NN);
        }
    }
}

// ---------------------------------------------------------------------------
extern "C" void kernel_launch(void* const* d_in, const int* in_sizes, int n_in,
                              void* d_out, int out_size, void* d_ws, size_t ws_size,
                              hipStream_t stream)
{
    const float* X  = (const float*)d_in[0];   // [512, 2048] fp32
    const int*   tg = (const int*)d_in[1];     // [512] int
    const float* LF = (const float*)d_in[2];   // [512, 128, 8] fp32
    float* out = (float*)d_out;                // 2 fp32 scalars

    char* ws = (char*)d_ws;
    float*    Gp      = (float*)ws;                          // 8 x 1 MB partials
    float*    ndiag   = (float*)(ws + (8u << 20));           // 8 x 512 fp32 = 16 KB
    float*    gsum    = (float*)(ws + (8u << 20) + 16384);
    float*    lsum    = (float*)(ws + (8u << 20) + 16388);
    unsigned* counter = (unsigned*)(ws + (8u << 20) + 16392);

    k_gram<<<512, 256, 0, stream>>>(X, Gp, ndiag, gsum, lsum, counter);
    k_mine_local<<<512, 256, 0, stream>>>(Gp, ndiag, tg, LF, gsum, lsum, counter, out);
}